// Round 16
// baseline (242.660 us; speedup 1.0000x reference)
//
#include <hip/hip_runtime.h>
#include <math.h>

#define HW 1024
#define RS 33            // padded row stride (32 px + 1 zero col)
#define GP 34            // zero guard pixels before each image
#define PB 1120          // padded pixels per batch image

typedef unsigned short u16;
typedef __attribute__((ext_vector_type(8))) short short8v;   // 8 bf16
typedef __attribute__((ext_vector_type(4))) float f32x4;
typedef __attribute__((ext_vector_type(16))) float f32x16;

__device__ __forceinline__ float elu_f(float x){ return x>0.f? x : (__expf(x)-1.f); }
__device__ __forceinline__ float sig_f(float x){ return 1.f/(1.f+__expf(-x)); }
__device__ __forceinline__ u16 f2bf(float f){ unsigned u=__float_as_uint(f); return (u16)((u + 0x7fffu + ((u>>16)&1u))>>16); }
__device__ __forceinline__ float bf2f(u16 h){ return __uint_as_float(((unsigned)h)<<16); }

__device__ __forceinline__ void gld16(const void* g, void* l) {
    __builtin_amdgcn_global_load_lds(
        (const __attribute__((address_space(1))) void*)g,
        (__attribute__((address_space(3))) void*)l, 16, 0, 0);
}

// ---------------------------------------------------------------------------
// Merged one-time weight convert + guard-slot zeroing (unchanged).
// ---------------------------------------------------------------------------
__global__ __launch_bounds__(256)
void wconv(const float* __restrict__ rw1, const float* __restrict__ rw2,
           const float* __restrict__ apw, const float* __restrict__ ocw,
           const float* __restrict__ oaw, const float* __restrict__ opw,
           const float* __restrict__ qkvw,
           u16* __restrict__ w1b, u16* __restrict__ w2b,
           u16* __restrict__ whs, u16* __restrict__ qws,
           u16* __restrict__ Eb,  u16* __restrict__ E2)
{
    const int i = blockIdx.x*256 + threadIdx.x;
    if (i < 98304) {                        // conv1 weights: 6*128 rows * 128 c
        const int layer = i >> 14;
        const int rem = i & 16383;
        const int r = rem >> 7, c = rem & 127;
        const float4 v = *(const float4*)(rw1 + (size_t)i*4);
        const float tv[4] = {v.x, v.y, v.z, v.w};
        const int g = (c & 63) >> 3, j = c & 7;
        const int s = g ^ (r & 7);
        #pragma unroll
        for (int tap = 0; tap < 4; ++tap) {
            const int ks = tap*2 + (c >> 6);
            w1b[((size_t)layer*128 + r)*512 + ks*64 + s*8 + j] = f2bf(tv[tap]);
        }
    } else if (i < 294912) {                // conv2 weights: 6*256 Bs-rows * 128 c
        const int ii = i - 98304;
        const int layer = ii >> 15;
        const int rem = ii & 32767;
        const int R = rem >> 7, c = rem & 127;
        const int by = R >> 7, r = R & 127;
        const int h = (r >> 6) & 1, f2 = (r >> 4) & 3, rr = r & 15;
        const int ch = (f2 < 2) ? (by*64 + h*32 + f2*16 + rr)
                                : (128 + by*64 + h*32 + (f2-2)*16 + rr);
        const float4 v = *(const float4*)(rw2 + ((size_t)layer*256 + ch)*512 + c*4);
        const float tv[4] = {v.x, v.y, v.z, v.w};
        const int g = (c & 63) >> 3, j = c & 7;
        const int s = g ^ (R & 7);
        #pragma unroll
        for (int tap = 0; tap < 4; ++tap) {
            const int ks = tap*2 + (c >> 6);
            w2b[((size_t)layer*256 + R)*512 + ks*64 + s*8 + j] = f2bf(tv[tap]);
        }
    } else if (i < 360448) {                // head 1x1 weights: 4*128*128, swizzled
        const int ii = i - 294912;
        const int m = ii >> 14;
        const int rem = ii & 16383;
        const int r = rem >> 7, k = rem & 127;
        const int ks = k >> 6, s = (k >> 3) & 7, j = k & 7;
        const int g = s ^ (r & 7);
        const int c = (ks << 6) + g*8 + j;
        const float* src = (m==0)? apw : (m==1)? ocw : (m==2)? oaw : opw;
        whs[ii] = f2bf(src[r*128 + c]);
    } else if (i < 385024) {                // qkv weights padded to 192 rows, swizzled
        const int ii = i - 360448;
        const int r = ii >> 7, k = ii & 127;
        const int ks = k >> 6, s = (k >> 3) & 7, j = k & 7;
        const int g = s ^ (r & 7);
        const int c = (ks << 6) + g*8 + j;
        qws[ii] = (r < 160) ? f2bf(qkvw[(size_t)r*130 + c]) : (u16)0;
    } else if (i < 483328) {                // guard-slot zeroing
        const int ii = i - 385024;
        const int half = ii / 49152;
        const int idx = ii % 49152;
        const int b = idx / 1536;
        const int rem = idx % 1536;
        const int g = rem >> 4, c8 = rem & 15;
        const int slot = (g < 34) ? g : (g < 65) ? (66 + 33*(g-34)) : (1089 + (g-65));
        u16* dst = (half ? E2 : Eb) + ((size_t)b*PB + slot)*128 + c8*8;
        uint4 z; z.x=0u; z.y=0u; z.z=0u; z.w=0u;
        *(uint4*)dst = z;
    }
}

// ---------------------------------------------------------------------------
// init (unchanged)
// ---------------------------------------------------------------------------
__global__ __launch_bounds__(256)
void init_k(const float* __restrict__ x, u16* __restrict__ Sb, u16* __restrict__ Eb)
{
    __shared__ float t[32][132];
    const int b = blockIdx.y, p0 = blockIdx.x*32;
    const int tid = threadIdx.x;
    const int cr = tid >> 3, p4 = (tid & 7)*4;
    #pragma unroll
    for (int cc = 0; cc < 128; cc += 32) {
        const float4 v = *(const float4*)(x + ((size_t)b*128 + cc + cr)*HW + p0 + p4);
        t[p4+0][cc+cr]=v.x; t[p4+1][cc+cr]=v.y; t[p4+2][cc+cr]=v.z; t[p4+3][cc+cr]=v.w;
    }
    __syncthreads();
    const int pr = tid >> 3, c4 = (tid & 7)*4;
    const int px = p0 + pr;
    const int pad = GP + px + (px>>5);
    #pragma unroll
    for (int cc = 0; cc < 128; cc += 32) {
        const int c = cc + c4;
        float4 v; v.x=t[pr][c]; v.y=t[pr][c+1]; v.z=t[pr][c+2]; v.w=t[pr][c+3];
        ushort4 s4;
        s4.x=f2bf(v.x); s4.y=f2bf(v.y); s4.z=f2bf(v.z); s4.w=f2bf(v.w);
        *(ushort4*)(Sb + ((size_t)b*PB + pad)*128 + c) = s4;
        ushort4 e;
        e.x=f2bf(elu_f(v.x)); e.y=f2bf(elu_f(v.y)); e.z=f2bf(elu_f(v.z)); e.w=f2bf(elu_f(v.w));
        *(ushort4*)(Eb + ((size_t)b*PB + pad)*128 + c) = e;
    }
}

// ---------------------------------------------------------------------------
// Unified conv2x2 GEMM: m97 geometry 128px x 128 Bs-rows, BK=64, 2-buffer
// 64KB LDS, T3-minimum schedule, XCD swizzle, setprio.
// EPI 0: out0 = bf16(elu(acc+bias)) padded              (conv1; grid (8,1,32))
// EPI 1: gate: o = Sio + t1*sig(t2); Sio=bf16(o);
//        out0 = bf16(elu(o)) padded                     (conv2; grid (8,2,32))
// ---------------------------------------------------------------------------
#define W2STAGE(ks, buf) do {                                                    \
    const int tap_ = (ks) >> 1;                                                  \
    const int off_ = (tap_>>1)*RS + (tap_&1) - RS - 1;                           \
    const int c0_  = ((ks) & 1) << 6;                                            \
    _Pragma("unroll")                                                            \
    for (int ca_=0; ca_<4; ++ca_) {                                              \
        const int row_ = ca_*32 + wv*8 + (lane>>3);                              \
        const int px_  = p0 + row_;                                              \
        const int pad_ = GP + px_ + (px_>>5);                                    \
        const int g_   = (lane&7) ^ (lane>>3);                                   \
        gld16(ebB + (size_t)(pad_ + off_)*128 + c0_ + g_*8,                      \
              (char*)As[buf] + (ca_*32 + wv*8)*128 + lane*16);                   \
    }                                                                            \
    _Pragma("unroll")                                                            \
    for (int cb_=0; cb_<4; ++cb_) {                                              \
        const int row_ = cb_*32 + wv*8 + (lane>>3);                              \
        gld16(wbB + (size_t)row_*512 + (ks)*64 + (lane&7)*8,                     \
              (char*)Bs[buf] + (cb_*32 + wv*8)*128 + lane*16);                   \
    }                                                                            \
} while(0)

#define W2COMP(buf) do {                                                         \
    _Pragma("unroll")                                                            \
    for (int k2_=0; k2_<2; ++k2_) {                                              \
        short8v wf_[4], pf_[4];                                                  \
        const int sl_ = ((k2_*4 + lg) ^ (lr & 7)) * 8;                           \
        _Pragma("unroll")                                                        \
        for (int f_=0; f_<4; ++f_)                                               \
            wf_[f_] = *(const short8v*)&Bs[buf][(chh*64 + f_*16 + lr)*64 + sl_]; \
        _Pragma("unroll")                                                        \
        for (int m_=0; m_<4; ++m_)                                               \
            pf_[m_] = *(const short8v*)&As[buf][(pxh*64 + m_*16 + lr)*64 + sl_]; \
        __builtin_amdgcn_s_setprio(1);                                           \
        _Pragma("unroll")                                                        \
        for (int f_=0; f_<4; ++f_)                                               \
            _Pragma("unroll")                                                    \
            for (int m_=0; m_<4; ++m_)                                           \
                acc[f_][m_] = __builtin_amdgcn_mfma_f32_16x16x32_bf16(wf_[f_], pf_[m_], acc[f_][m_],0,0,0); \
        __builtin_amdgcn_s_setprio(0);                                           \
    }                                                                            \
} while(0)

template<int EPI>
__global__ __launch_bounds__(256)
void convw(const u16* __restrict__ Wb, const float* __restrict__ bias,
           const u16* __restrict__ Ein, u16* __restrict__ out0,
           u16* __restrict__ Sio)
{
    constexpr int NS = 8;              // K=512, BK=64, BM=128, NB=128
    constexpr int NY = (EPI==1) ? 2 : 1;
    constexpr int NWG = 8*NY*32;
    __shared__ u16 As[2][128*64];      // 32 KB
    __shared__ u16 Bs[2][128*64];      // 32 KB
    const int tid = threadIdx.x;
    int w = blockIdx.x + (blockIdx.y << 3) + blockIdx.z * (8*NY);
    w = (w & 7)*(NWG >> 3) + (w >> 3);
    const int p0  = (w & 7)*128;
    const int byy = (EPI==1) ? ((w >> 3) & 1) : 0;
    const int b   = (EPI==1) ? (w >> 4) : (w >> 3);
    const int cb0 = byy*64;
    const int wv = tid>>6, lane = tid&63, lr = lane&15, lg = lane>>4;
    const int pxh = wv&1, chh = wv>>1;
    const u16* ebB = Ein + (size_t)b*PB*128;
    const u16* wbB = Wb + (size_t)byy*128*512;
    f32x4 acc[4][4] = {};

    W2STAGE(0, 0);
    asm volatile("s_waitcnt vmcnt(0)" ::: "memory");
    __builtin_amdgcn_s_barrier();
    __builtin_amdgcn_sched_barrier(0);
    #pragma unroll
    for (int ks = 0; ks < NS; ++ks) {
        if (ks + 1 < NS) W2STAGE(ks+1, (ks+1)&1);
        W2COMP(ks&1);
        asm volatile("s_waitcnt vmcnt(0)" ::: "memory");
        __builtin_amdgcn_s_barrier();
        __builtin_amdgcn_sched_barrier(0);
    }

    if constexpr (EPI == 1) {
        // gate epilogue: acc[f][m] (f=0,1 t1; f=2,3 t2)
        #pragma unroll
        for (int f=0; f<2; ++f) {
            const int c = cb0 + chh*32 + f*16 + lg*4;
            const float4 b1 = *(const float4*)(bias + c);
            const float4 b2 = *(const float4*)(bias + 128 + c);
            #pragma unroll
            for (int m=0; m<4; ++m) {
                const int px = p0 + pxh*64 + m*16 + lr;
                const int pad = GP + px + (px>>5);
                u16* sp = Sio + ((size_t)b*PB + pad)*128 + c;
                const ushort4 sv = *(const ushort4*)sp;
                const float o0 = bf2f(sv.x) + (acc[f][m][0]+b1.x)*sig_f(acc[f+2][m][0]+b2.x);
                const float o1 = bf2f(sv.y) + (acc[f][m][1]+b1.y)*sig_f(acc[f+2][m][1]+b2.y);
                const float o2 = bf2f(sv.z) + (acc[f][m][2]+b1.z)*sig_f(acc[f+2][m][2]+b2.z);
                const float o3 = bf2f(sv.w) + (acc[f][m][3]+b1.w)*sig_f(acc[f+2][m][3]+b2.w);
                ushort4 so;
                so.x=f2bf(o0); so.y=f2bf(o1); so.z=f2bf(o2); so.w=f2bf(o3);
                *(ushort4*)sp = so;
                ushort4 e;
                e.x=f2bf(elu_f(o0)); e.y=f2bf(elu_f(o1)); e.z=f2bf(elu_f(o2)); e.w=f2bf(elu_f(o3));
                *(ushort4*)(out0 + ((size_t)b*PB + pad)*128 + c) = e;
            }
        }
    } else {
        #pragma unroll
        for (int f=0; f<4; ++f) {
            const int c = chh*64 + f*16 + lg*4;
            const float4 bb = *(const float4*)(bias + c);
            #pragma unroll
            for (int m=0; m<4; ++m) {
                const int px = p0 + pxh*64 + m*16 + lr;
                const int pad = GP + px + (px>>5);
                ushort4 e;
                e.x=f2bf(elu_f(acc[f][m][0]+bb.x));
                e.y=f2bf(elu_f(acc[f][m][1]+bb.y));
                e.z=f2bf(elu_f(acc[f][m][2]+bb.z));
                e.w=f2bf(elu_f(acc[f][m][3]+bb.w));
                *(ushort4*)(out0 + ((size_t)b*PB + pad)*128 + c) = e;
            }
        }
    }
}

// ---------------------------------------------------------------------------
// Head 1x1 GEMM (unchanged r12)
// ---------------------------------------------------------------------------
template<int EPI, int DUAL>
__global__ __launch_bounds__(256)
void headg(const u16* __restrict__ Wh,
           const float* __restrict__ bias0, const float* __restrict__ bias1,
           const u16* __restrict__ in0, const u16* __restrict__ in1,
           u16* __restrict__ dst0, u16* __restrict__ dst1,
           const u16* __restrict__ aux, const float* __restrict__ xres,
           float* __restrict__ fout)
{
    constexpr int NY = DUAL ? 2 : 1;
    constexpr int NWG = 16*NY*32;
    __shared__ u16 As[2][64*64];
    __shared__ u16 Bs[2][128*64];
    const int tid = threadIdx.x;
    int w = blockIdx.x + (blockIdx.y << 4) + blockIdx.z * (16*NY);
    w = (w & 7)*(NWG >> 3) + (w >> 3);
    const int p0 = (w & 15)*64;
    const int by = DUAL ? ((w >> 4) & 1) : 0;
    const int b  = DUAL ? (w >> 5) : (w >> 4);
    const int wv = tid>>6, lane = tid&63, lr = lane&15, lg = lane>>4;
    const int pxh = wv&1, chh = wv>>1;
    const u16* wsrcB = Wh + (size_t)by*16384;
    const float* bias = (DUAL && by) ? bias1 : bias0;
    const u16* inB = (DUAL && by) ? in1 : in0;
    f32x4 acc[4][2] = {};

    auto HSTAGE = [&](int ks, int buf) {
        #pragma unroll
        for (int ca=0; ca<2; ++ca) {
            const int row = ca*32 + wv*8 + (lane>>3);
            const int px = p0 + row;
            size_t aoff;
            if (DUAL && by) aoff = (size_t)b*PB + (GP + px + (px>>5));
            else            aoff = (size_t)b*HW + px;
            const int g = (lane&7) ^ (lane>>3);
            gld16(inB + aoff*128 + ks*64 + g*8,
                  (char*)As[buf] + (ca*32 + wv*8)*128 + lane*16);
        }
        #pragma unroll
        for (int cb=0; cb<4; ++cb) {
            const int row = cb*32 + wv*8 + (lane>>3);
            gld16(wsrcB + (size_t)row*128 + ks*64 + (lane&7)*8,
                  (char*)Bs[buf] + (cb*32 + wv*8)*128 + lane*16);
        }
    };
    auto HCOMP = [&](int buf) {
        #pragma unroll
        for (int k2=0; k2<2; ++k2) {
            short8v wf[4], pf[2];
            const int sl = ((k2*4 + lg) ^ (lr & 7)) * 8;
            #pragma unroll
            for (int f=0; f<4; ++f)
                wf[f] = *(const short8v*)&Bs[buf][(chh*64 + f*16 + lr)*64 + sl];
            #pragma unroll
            for (int m=0; m<2; ++m)
                pf[m] = *(const short8v*)&As[buf][(pxh*32 + m*16 + lr)*64 + sl];
            __builtin_amdgcn_s_setprio(1);
            #pragma unroll
            for (int f=0; f<4; ++f)
                #pragma unroll
                for (int m=0; m<2; ++m)
                    acc[f][m] = __builtin_amdgcn_mfma_f32_16x16x32_bf16(wf[f], pf[m], acc[f][m],0,0,0);
            __builtin_amdgcn_s_setprio(0);
        }
    };

    HSTAGE(0, 0);
    HSTAGE(1, 1);
    asm volatile("s_waitcnt vmcnt(6)" ::: "memory");
    __builtin_amdgcn_s_barrier();
    __builtin_amdgcn_sched_barrier(0);
    HCOMP(0);
    asm volatile("s_waitcnt vmcnt(0)" ::: "memory");
    __builtin_amdgcn_s_barrier();
    __builtin_amdgcn_sched_barrier(0);
    HCOMP(1);

    #pragma unroll
    for (int f=0; f<4; ++f) {
        const int c = chh*64 + f*16 + lg*4;
        #pragma unroll
        for (int m=0; m<2; ++m) {
            const int px = p0 + pxh*32 + m*16 + lr;
            if constexpr (EPI == 3) {
                const float* bp = bias + c;
                #pragma unroll
                for (int r=0; r<4; ++r) {
                    const size_t o = ((size_t)b*128 + c + r)*HW + px;
                    fout[o] = elu_f(acc[f][m][r] + bp[r]) + xres[o];
                }
            } else {
                const float4 bb = *(const float4*)(bias + c);
                const float v0=acc[f][m][0]+bb.x, v1=acc[f][m][1]+bb.y;
                const float v2=acc[f][m][2]+bb.z, v3=acc[f][m][3]+bb.w;
                ushort4 e;
                if constexpr (EPI == 2) {
                    const ushort4 c4 = *(const ushort4*)(aux + ((size_t)b*HW+px)*128 + c);
                    e.x = f2bf(elu_f(bf2f(c4.x) + elu_f(v0)));
                    e.y = f2bf(elu_f(bf2f(c4.y) + elu_f(v1)));
                    e.z = f2bf(elu_f(bf2f(c4.z) + elu_f(v2)));
                    e.w = f2bf(elu_f(bf2f(c4.w) + elu_f(v3)));
                } else {
                    e.x=f2bf(elu_f(v0)); e.y=f2bf(elu_f(v1));
                    e.z=f2bf(elu_f(v2)); e.w=f2bf(elu_f(v3));
                }
                u16* dst = (DUAL && by) ? dst1 : dst0;
                *(ushort4*)(dst + ((size_t)b*HW+px)*128 + c) = e;
            }
        }
    }
}

// ---------------------------------------------------------------------------
// qkv GEMM (unchanged r12)
// ---------------------------------------------------------------------------
__global__ __launch_bounds__(256)
void qkvg(const u16* __restrict__ Wq, const float* __restrict__ qkvw,
          const float* __restrict__ bias, const u16* __restrict__ Sb,
          u16* __restrict__ qo, u16* __restrict__ ko, u16* __restrict__ vo)
{
    __shared__ u16 As[2][64*64];
    __shared__ u16 Bs[2][192*64];
    const int tid = threadIdx.x;
    int w = blockIdx.x + (blockIdx.z << 4);
    w = (w & 7)*64 + (w >> 3);
    const int p0 = (w & 15)*64;
    const int b  = w >> 4;
    const int wv = tid>>6, lane = tid&63, lr = lane&15, lg = lane>>4;
    const int pxh = wv&1, chh = wv>>1;
    const u16* ebB = Sb + (size_t)b*PB*128;
    f32x4 acc[6][2] = {};

    auto QSTAGE = [&](int ks, int buf) {
        #pragma unroll
        for (int ca=0; ca<2; ++ca) {
            const int row = ca*32 + wv*8 + (lane>>3);
            const int px = p0 + row;
            const int pad = GP + px + (px>>5);
            const int g = (lane&7) ^ (lane>>3);
            gld16(ebB + (size_t)pad*128 + ks*64 + g*8,
                  (char*)As[buf] + (ca*32 + wv*8)*128 + lane*16);
        }
        #pragma unroll
        for (int cb=0; cb<6; ++cb) {
            const int row = cb*32 + wv*8 + (lane>>3);
            gld16(Wq + (size_t)row*128 + ks*64 + (lane&7)*8,
                  (char*)Bs[buf] + (cb*32 + wv*8)*128 + lane*16);
        }
    };
    auto QCOMP = [&](int buf) {
        #pragma unroll
        for (int k2=0; k2<2; ++k2) {
            short8v wf[6], pf[2];
            const int sl = ((k2*4 + lg) ^ (lr & 7)) * 8;
            #pragma unroll
            for (int f=0; f<6; ++f)
                wf[f] = *(const short8v*)&Bs[buf][(chh*96 + f*16 + lr)*64 + sl];
            #pragma unroll
            for (int m=0; m<2; ++m)
                pf[m] = *(const short8v*)&As[buf][(pxh*32 + m*16 + lr)*64 + sl];
            __builtin_amdgcn_s_setprio(1);
            #pragma unroll
            for (int f=0; f<6; ++f)
                #pragma unroll
                for (int m=0; m<2; ++m)
                    acc[f][m] = __builtin_amdgcn_mfma_f32_16x16x32_bf16(wf[f], pf[m], acc[f][m],0,0,0);
            __builtin_amdgcn_s_setprio(0);
        }
    };

    QSTAGE(0, 0);
    QSTAGE(1, 1);
    asm volatile("s_waitcnt vmcnt(8)" ::: "memory");
    __builtin_amdgcn_s_barrier();
    __builtin_amdgcn_sched_barrier(0);
    QCOMP(0);
    asm volatile("s_waitcnt vmcnt(0)" ::: "memory");
    __builtin_amdgcn_s_barrier();
    __builtin_amdgcn_sched_barrier(0);
    QCOMP(1);

    #pragma unroll
    for (int f=0; f<6; ++f) {
        const int row0 = chh*96 + f*16;
        if (row0 >= 160) continue;
        #pragma unroll
        for (int m=0; m<2; ++m) {
            const int px = p0 + pxh*32 + m*16 + lr;
            const float pyv = (float)(px>>5)*0.03125f - 0.5f;
            const float pxv = (float)(px&31)*0.03125f - 0.5f;
            #pragma unroll
            for (int r=0; r<4; ++r) {
                const int mm = row0 + lg*4 + r;
                const float val = acc[f][m][r] + bias[mm]
                                + qkvw[(size_t)mm*130 + 128]*pyv
                                + qkvw[(size_t)mm*130 + 129]*pxv;
                if (mm < 16)      qo[((size_t)b*HW+px)*16 + mm]        = f2bf(0.25f*val);
                else if (mm < 32) ko[((size_t)b*HW+px)*16 + (mm-16)]   = f2bf(val);
                else              vo[((size_t)b*128 + (mm-32))*HW + px] = f2bf(val);
            }
        }
    }
}

// ---------------------------------------------------------------------------
// MFMA causal attention (unchanged r12: hi/lo pairing, 36/20 strides)
// ---------------------------------------------------------------------------
__global__ __launch_bounds__(256)
void attn_mfma(const u16* __restrict__ qb, const u16* __restrict__ kb,
               const u16* __restrict__ vb, u16* __restrict__ ob)
{
    __shared__ u16 ks_[2][32*20];
    __shared__ u16 vs_[2][128*36];
    const int tid = threadIdx.x;
    const int bid = blockIdx.x;              // 0..511
    const int s  = bid >> 5;
    const int b  = bid & 31;
    const int tp = (s < 8) ? (15 - s) : (s - 8);
    const int wv = tid>>6, lane = tid&63;
    const int lq = lane&31, hf = lane>>5;
    const int qt = tp*2 + (wv&1);
    const int dh = wv>>1;
    const int q0 = qt*32;
    const int NC = tp*2 + 2;

    const short8v Qf = *(const short8v*)(qb + ((size_t)b*HW + q0 + lq)*16 + hf*8);
    f32x16 acc[2] = {{},{}};
    float mrun = -1e30f, lrun = 0.f;
    unsigned diagm = 0;
    #pragma unroll
    for (int r=0; r<16; ++r) {
        const int row = (r&3) + 8*(r>>2) + 4*hf;
        diagm |= (row <= lq) ? (1u<<r) : 0u;
    }
    const f32x16 zc = {};

    const int vrow = tid>>2, vg = tid&3;
    const int krow = tid>>1, kg = tid&1;
    const u16* vbb = vb + (size_t)b*128*HW;
    const u16* kbb = kb + (size_t)b*HW*16;
    uint4 rv0A, rv1A, rkA, rv0B, rv1B, rkB;

#define AGLD(c, RV0, RV1, RK) do {                                             \
    const int kv0_ = (c)*32;                                                   \
    RV0 = *(const uint4*)(vbb + (size_t)vrow*HW + kv0_ + vg*8);                \
    RV1 = *(const uint4*)(vbb + (size_t)(64+vrow)*HW + kv0_ + vg*8);           \
    if (tid < 64) RK = *(const uint4*)(kbb + (size_t)(kv0_ + krow)*16 + kg*8); \
} while(0)
#define ASST(buf, RV0, RV1, RK) do {                                           \
    *(uint4*)&vs_[buf][vrow*36 + vg*8] = RV0;                                  \
    *(uint4*)&vs_[buf][(64+vrow)*36 + vg*8] = RV1;                             \
    if (tid < 64) *(uint4*)&ks_[buf][krow*20 + kg*8] = RK;                     \
} while(0)

    auto CHUNK = [&](int buf, int cc) {
        if (cc > qt) return;
        const short8v Kf = *(const short8v*)&ks_[buf][lq*20 + hf*8];
        f32x16 st = __builtin_amdgcn_mfma_f32_32x32x16_bf16(Kf, Qf, zc, 0,0,0);
        if (cc == qt) {
            #pragma unroll
            for (int r=0;r<16;++r) st[r] = ((diagm>>r)&1) ? st[r] : -1e30f;
        }
        float mc = st[0];
        #pragma unroll
        for (int r=1;r<16;++r) mc = fmaxf(mc, st[r]);
        mc = fmaxf(mc, __shfl_xor(mc, 32));
        if (!__all(mc <= mrun)) {
            const float mnew = fmaxf(mrun, mc);
            const float corr = __expf(mrun - mnew);
            lrun *= corr;
            #pragma unroll
            for (int f=0;f<2;++f)
                #pragma unroll
                for (int r=0;r<16;++r) acc[f][r] *= corr;
            mrun = mnew;
        }
        float ps[16]; float lsum = 0.f;
        #pragma unroll
        for (int r=0;r<16;++r){ ps[r]=__expf(st[r]-mrun); lsum += ps[r]; }
        lrun += lsum + __shfl_xor(lsum, 32);
        unsigned pk[8], sw[8];
        #pragma unroll
        for (int i=0;i<8;++i)
            pk[i] = (unsigned)f2bf(ps[2*i]) | ((unsigned)f2bf(ps[2*i+1])<<16);
        #pragma unroll
        for (int i=0;i<8;++i) sw[i] = __shfl_xor(pk[i], 32);
        union { unsigned u[4]; short8v v; } B1, B2;
        B1.u[0]=hf?sw[2]:pk[0]; B1.u[1]=hf?sw[3]:pk[1];
        B1.u[2]=hf?pk[2]:sw[0]; B1.u[3]=hf?pk[3]:sw[1];
        B2.u[0]=hf?sw[6]:pk[4]; B2.u[1]=hf?sw[7]:pk[5];
        B2.u[2]=hf?pk[6]:sw[4]; B2.u[3]=hf?pk[7]:sw[5];
        #pragma unroll
        for (int f=0;f<2;++f) {
            const int fg = dh*2 + f;
            const short8v A1 = *(const short8v*)&vs_[buf][(fg*32+lq)*36 + hf*8];
            const short8v A2 = *(const short8v*)&vs_[buf][(fg*32+lq)*36 + 16 + hf*8];
            acc[f] = __builtin_amdgcn_mfma_f32_32x32x16_bf16(A1, B1.v, acc[f],0,0,0);
            acc[f] = __builtin_amdgcn_mfma_f32_32x32x16_bf16(A2, B2.v, acc[f],0,0,0);
        }
    };

    AGLD(0, rv0A, rv1A, rkA); ASST(0, rv0A, rv1A, rkA);
    AGLD(1, rv0B, rv1B, rkB);
    __syncthreads();
    for (int c = 0; c < NC; c += 2) {
        CHUNK(0, c);
        ASST(1, rv0B, rv1B, rkB);
        if (c+2 < NC) AGLD(c+2, rv0A, rv1A, rkA);
        __syncthreads();
        CHUNK(1, c+1);
        if (c+2 < NC) {
            ASST(0, rv0A, rv1A, rkA);
            if (c+3 < NC) AGLD(c+3, rv0B, rv1B, rkB);
        }
        __syncthreads();
    }
#undef AGLD
#undef ASST

    const float inv = 1.f / lrun;
    u16* orow = ob + ((size_t)b*HW + q0 + lq)*128;
    #pragma unroll
    for (int f=0; f<2; ++f) {
        #pragma unroll
        for (int g=0; g<4; ++g) {
            const int d0 = (dh*2+f)*32 + 8*g + 4*hf;
            ushort4 o4;
            o4.x = f2bf(acc[f][g*4+0]*inv);
            o4.y = f2bf(acc[f][g*4+1]*inv);
            o4.z = f2bf(acc[f][g*4+2]*inv);
            o4.w = f2bf(acc[f][g*4+3]*inv);
            *(ushort4*)(orow + d0) = o4;
        }
    }
}

extern "C" void kernel_launch(void* const* d_in, const int* in_sizes, int n_in,
                              void* d_out, int out_size, void* d_ws, size_t ws_size,
                              hipStream_t stream) {
    const float* x    = (const float*)d_in[0];
    const float* rw1  = (const float*)d_in[1];
    const float* rb1  = (const float*)d_in[2];
    const float* rw2  = (const float*)d_in[3];
    const float* rb2  = (const float*)d_in[4];
    const float* qkvw = (const float*)d_in[5];
    const float* qkvb = (const float*)d_in[6];
    const float* apw  = (const float*)d_in[7];
    const float* apb  = (const float*)d_in[8];
    const float* ocw  = (const float*)d_in[9];
    const float* ocb  = (const float*)d_in[10];
    const float* oaw  = (const float*)d_in[11];
    const float* oab  = (const float*)d_in[12];
    const float* opw  = (const float*)d_in[13];
    const float* opb  = (const float*)d_in[14];
    float* out = (float*)d_out;
    float* ws = (float*)d_ws;

    u16* Sb  = (u16*)ws;
    u16* Eb  = (u16*)(ws + 2293760);
    u16* E2  = (u16*)(ws + 4587520);
    u16* ob  = (u16*)(ws + 6881280);
    u16* qb  = (u16*)(ws + 8978432);
    u16* kb  = (u16*)(ws + 9240576);
    u16* vb  = (u16*)(ws + 9502720);
    u16* w1b = (u16*)(ws + 11599872);
    u16* w2b = (u16*)(ws + 11796480);
    u16* whs = (u16*)(ws + 12189696);
    u16* qws = (u16*)(ws + 12222464);
    u16* Ea  = (u16*)(ws + 12234752);
    u16* c1p = (u16*)(ws + 14331904);
    u16* Es  = ob;

    dim3 blk(256);
    wconv<<<1888, blk, 0, stream>>>(rw1, rw2, apw, ocw, oaw, opw, qkvw,
                                    w1b, w2b, whs, qws, Eb, E2);
    init_k<<<dim3(32, 32), blk, 0, stream>>>(x, Sb, Eb);
    for (int i = 0; i < 6; ++i) {
        convw<0><<<dim3(8,1,32), blk, 0, stream>>>(
            w1b + (size_t)i*65536, rb1 + i*128, Eb, E2, nullptr);
        convw<1><<<dim3(8,2,32), blk, 0, stream>>>(
            w2b + (size_t)i*131072, rb2 + i*256, E2, Eb, Sb);
    }
    qkvg<<<dim3(16,1,32), blk, 0, stream>>>(qws, qkvw, qkvb, Sb, qb, kb, vb);
    attn_mfma<<<512, blk, 0, stream>>>(qb, kb, vb, ob);
    headg<0,1><<<dim3(16,2,32), blk, 0, stream>>>(
        whs, apb, ocb, ob, Eb, Ea, c1p, nullptr, nullptr, nullptr);
    headg<2,0><<<dim3(16,1,32), blk, 0, stream>>>(
        whs + 32768, oab, nullptr, Ea, nullptr, Es, nullptr, c1p, nullptr, nullptr);
    headg<3,0><<<dim3(16,1,32), blk, 0, stream>>>(
        whs + 49152, opb, nullptr, Es, nullptr, nullptr, nullptr, nullptr, x, out);
}

// Round 17
// 238.038 us; speedup vs baseline: 1.0194x; 1.0194x over previous
//
#include <hip/hip_runtime.h>
#include <math.h>

#define HW 1024
#define RS 33            // padded row stride (32 px + 1 zero col)
#define GP 34            // zero guard pixels before each image
#define PB 1120          // padded pixels per batch image

typedef unsigned short u16;
typedef __attribute__((ext_vector_type(8))) short short8v;   // 8 bf16
typedef __attribute__((ext_vector_type(4))) float f32x4;
typedef __attribute__((ext_vector_type(16))) float f32x16;

__device__ __forceinline__ float elu_f(float x){ return x>0.f? x : (__expf(x)-1.f); }
__device__ __forceinline__ float sig_f(float x){ return 1.f/(1.f+__expf(-x)); }
__device__ __forceinline__ u16 f2bf(float f){ unsigned u=__float_as_uint(f); return (u16)((u + 0x7fffu + ((u>>16)&1u))>>16); }
__device__ __forceinline__ float bf2f(u16 h){ return __uint_as_float(((unsigned)h)<<16); }

__device__ __forceinline__ void gld16(const void* g, void* l) {
    __builtin_amdgcn_global_load_lds(
        (const __attribute__((address_space(1))) void*)g,
        (__attribute__((address_space(3))) void*)l, 16, 0, 0);
}

// ---------------------------------------------------------------------------
// Merged one-time weight convert + guard-slot zeroing.
// ---------------------------------------------------------------------------
__global__ __launch_bounds__(256)
void wconv(const float* __restrict__ rw1, const float* __restrict__ rw2,
           const float* __restrict__ apw, const float* __restrict__ ocw,
           const float* __restrict__ oaw, const float* __restrict__ opw,
           const float* __restrict__ qkvw,
           u16* __restrict__ w1b, u16* __restrict__ w2b,
           u16* __restrict__ whs, u16* __restrict__ qws,
           u16* __restrict__ Eb,  u16* __restrict__ E2)
{
    const int i = blockIdx.x*256 + threadIdx.x;
    if (i < 98304) {                        // conv1 weights: 6*128 rows * 128 c
        const int layer = i >> 14;
        const int rem = i & 16383;
        const int r = rem >> 7, c = rem & 127;
        const float4 v = *(const float4*)(rw1 + (size_t)i*4);
        const float tv[4] = {v.x, v.y, v.z, v.w};
        const int g = (c & 63) >> 3, j = c & 7;
        const int s = g ^ (r & 7);
        #pragma unroll
        for (int tap = 0; tap < 4; ++tap) {
            const int ks = tap*2 + (c >> 6);
            w1b[((size_t)layer*128 + r)*512 + ks*64 + s*8 + j] = f2bf(tv[tap]);
        }
    } else if (i < 294912) {                // conv2 weights: 6*256 Bs-rows * 128 c
        const int ii = i - 98304;
        const int layer = ii >> 15;
        const int rem = ii & 32767;
        const int R = rem >> 7, c = rem & 127;
        const int by = R >> 7, r = R & 127;
        const int h = (r >> 6) & 1, f2 = (r >> 4) & 3, rr = r & 15;
        const int ch = (f2 < 2) ? (by*64 + h*32 + f2*16 + rr)
                                : (128 + by*64 + h*32 + (f2-2)*16 + rr);
        const float4 v = *(const float4*)(rw2 + ((size_t)layer*256 + ch)*512 + c*4);
        const float tv[4] = {v.x, v.y, v.z, v.w};
        const int g = (c & 63) >> 3, j = c & 7;
        const int s = g ^ (R & 7);
        #pragma unroll
        for (int tap = 0; tap < 4; ++tap) {
            const int ks = tap*2 + (c >> 6);
            w2b[((size_t)layer*256 + R)*512 + ks*64 + s*8 + j] = f2bf(tv[tap]);
        }
    } else if (i < 360448) {                // head 1x1 weights: 4*128*128, swizzled
        const int ii = i - 294912;
        const int m = ii >> 14;
        const int rem = ii & 16383;
        const int r = rem >> 7, k = rem & 127;
        const int ks = k >> 6, s = (k >> 3) & 7, j = k & 7;
        const int g = s ^ (r & 7);
        const int c = (ks << 6) + g*8 + j;
        const float* src = (m==0)? apw : (m==1)? ocw : (m==2)? oaw : opw;
        whs[ii] = f2bf(src[r*128 + c]);
    } else if (i < 385024) {                // qkv weights padded to 192 rows, swizzled
        const int ii = i - 360448;
        const int r = ii >> 7, k = ii & 127;
        const int ks = k >> 6, s = (k >> 3) & 7, j = k & 7;
        const int g = s ^ (r & 7);
        const int c = (ks << 6) + g*8 + j;
        qws[ii] = (r < 160) ? f2bf(qkvw[(size_t)r*130 + c]) : (u16)0;
    } else if (i < 483328) {                // guard-slot zeroing
        const int ii = i - 385024;
        const int half = ii / 49152;
        const int idx = ii % 49152;
        const int b = idx / 1536;
        const int rem = idx % 1536;
        const int g = rem >> 4, c8 = rem & 15;
        const int slot = (g < 34) ? g : (g < 65) ? (66 + 33*(g-34)) : (1089 + (g-65));
        u16* dst = (half ? E2 : Eb) + ((size_t)b*PB + slot)*128 + c8*8;
        uint4 z; z.x=0u; z.y=0u; z.z=0u; z.w=0u;
        *(uint4*)dst = z;
    }
}

// ---------------------------------------------------------------------------
// init
// ---------------------------------------------------------------------------
__global__ __launch_bounds__(256)
void init_k(const float* __restrict__ x, u16* __restrict__ Sb, u16* __restrict__ Eb)
{
    __shared__ float t[32][132];
    const int b = blockIdx.y, p0 = blockIdx.x*32;
    const int tid = threadIdx.x;
    const int cr = tid >> 3, p4 = (tid & 7)*4;
    #pragma unroll
    for (int cc = 0; cc < 128; cc += 32) {
        const float4 v = *(const float4*)(x + ((size_t)b*128 + cc + cr)*HW + p0 + p4);
        t[p4+0][cc+cr]=v.x; t[p4+1][cc+cr]=v.y; t[p4+2][cc+cr]=v.z; t[p4+3][cc+cr]=v.w;
    }
    __syncthreads();
    const int pr = tid >> 3, c4 = (tid & 7)*4;
    const int px = p0 + pr;
    const int pad = GP + px + (px>>5);
    #pragma unroll
    for (int cc = 0; cc < 128; cc += 32) {
        const int c = cc + c4;
        float4 v; v.x=t[pr][c]; v.y=t[pr][c+1]; v.z=t[pr][c+2]; v.w=t[pr][c+3];
        ushort4 s4;
        s4.x=f2bf(v.x); s4.y=f2bf(v.y); s4.z=f2bf(v.z); s4.w=f2bf(v.w);
        *(ushort4*)(Sb + ((size_t)b*PB + pad)*128 + c) = s4;
        ushort4 e;
        e.x=f2bf(elu_f(v.x)); e.y=f2bf(elu_f(v.y)); e.z=f2bf(elu_f(v.z)); e.w=f2bf(elu_f(v.w));
        *(ushort4*)(Eb + ((size_t)b*PB + pad)*128 + c) = e;
    }
}

// ---------------------------------------------------------------------------
// conv1: 64-px tile, 3-buffer counted-vmcnt convg (r12/r15-proven).
// ---------------------------------------------------------------------------
#define GSTAGE(ks, buf) do {                                                     \
    const int tap_ = (ks) >> 1;                                                  \
    const int off_ = (tap_>>1)*RS + (tap_&1) - RS - 1;                           \
    const int c0_  = ((ks) & 1) << 6;                                            \
    _Pragma("unroll")                                                            \
    for (int ca_=0; ca_<2; ++ca_) {                                              \
        const int row_ = ca_*32 + wv*8 + (lane>>3);                              \
        const int px_  = p0 + row_;                                              \
        const int pad_ = GP + px_ + (px_>>5);                                    \
        const int g_   = (lane&7) ^ (lane>>3);                                   \
        gld16(ebB + (size_t)(pad_ + off_)*128 + c0_ + g_*8,                      \
              (char*)As[buf] + (ca_*32 + wv*8)*128 + lane*16);                   \
    }                                                                            \
    _Pragma("unroll")                                                            \
    for (int cb_=0; cb_<4; ++cb_) {                                              \
        const int row_ = cb_*32 + wv*8 + (lane>>3);                              \
        gld16(wbB + (size_t)row_*512 + (ks)*64 + (lane&7)*8,                     \
              (char*)Bs[buf] + (cb_*32 + wv*8)*128 + lane*16);                   \
    }                                                                            \
} while(0)

#define GCOMP(buf) do {                                                          \
    _Pragma("unroll")                                                            \
    for (int k2_=0; k2_<2; ++k2_) {                                              \
        short8v wf_[4], pf_[2];                                                  \
        const int sl_ = ((k2_*4 + lg) ^ (lr & 7)) * 8;                           \
        _Pragma("unroll")                                                        \
        for (int f_=0; f_<4; ++f_)                                               \
            wf_[f_] = *(const short8v*)&Bs[buf][(chh*64 + f_*16 + lr)*64 + sl_]; \
        _Pragma("unroll")                                                        \
        for (int m_=0; m_<2; ++m_)                                               \
            pf_[m_] = *(const short8v*)&As[buf][(pxh*32 + m_*16 + lr)*64 + sl_]; \
        __builtin_amdgcn_s_setprio(1);                                           \
        _Pragma("unroll")                                                        \
        for (int f_=0; f_<4; ++f_)                                               \
            _Pragma("unroll")                                                    \
            for (int m_=0; m_<2; ++m_)                                           \
                acc[f_][m_] = __builtin_amdgcn_mfma_f32_16x16x32_bf16(wf_[f_], pf_[m_], acc[f_][m_],0,0,0); \
        __builtin_amdgcn_s_setprio(0);                                           \
    }                                                                            \
} while(0)

__global__ __launch_bounds__(256)
void convg(const u16* __restrict__ Wb, const float* __restrict__ bias,
           const u16* __restrict__ Ein, u16* __restrict__ out0)
{
    constexpr int NS = 8;              // K=512, BK=64, BM=64
    __shared__ u16 As[3][64*64];
    __shared__ u16 Bs[3][128*64];
    const int tid = threadIdx.x;
    int w = blockIdx.x + (blockIdx.z << 4);
    w = (w & 7)*64 + (w >> 3);
    const int p0 = (w & 15)*64;
    const int b  = w >> 4;
    const int wv = tid>>6, lane = tid&63, lr = lane&15, lg = lane>>4;
    const int pxh = wv&1, chh = wv>>1;
    const u16* ebB = Ein + (size_t)b*PB*128;
    const u16* wbB = Wb;
    f32x4 acc[4][2] = {};

    GSTAGE(0, 0);
    GSTAGE(1, 1);
    #pragma unroll
    for (int ks = 0; ks < NS; ++ks) {
        if (ks < NS-1) asm volatile("s_waitcnt vmcnt(6)" ::: "memory");
        else           asm volatile("s_waitcnt vmcnt(0)" ::: "memory");
        __builtin_amdgcn_s_barrier();
        __builtin_amdgcn_sched_barrier(0);
        if (ks + 2 < NS) GSTAGE(ks+2, (ks+2)%3);
        GCOMP(ks%3);
    }

    #pragma unroll
    for (int f=0; f<4; ++f) {
        const int c = chh*64 + f*16 + lg*4;
        const float4 bb = *(const float4*)(bias + c);
        #pragma unroll
        for (int m=0; m<2; ++m) {
            const int px = p0 + pxh*32 + m*16 + lr;
            const int pad = GP + px + (px>>5);
            ushort4 e;
            e.x=f2bf(elu_f(acc[f][m][0]+bb.x));
            e.y=f2bf(elu_f(acc[f][m][1]+bb.y));
            e.z=f2bf(elu_f(acc[f][m][2]+bb.z));
            e.w=f2bf(elu_f(acc[f][m][3]+bb.w));
            *(ushort4*)(out0 + ((size_t)b*PB + pad)*128 + c) = e;
        }
    }
}

// ---------------------------------------------------------------------------
// conv2: m97-geometry 128px x 128 Bs-rows tile, BK=64, 2-buffer 64KB LDS,
// T3-minimum schedule, XCD swizzle, setprio. Gate epilogue.
// ---------------------------------------------------------------------------
#define W2STAGE(ks, buf) do {                                                    \
    const int tap_ = (ks) >> 1;                                                  \
    const int off_ = (tap_>>1)*RS + (tap_&1) - RS - 1;                           \
    const int c0_  = ((ks) & 1) << 6;                                            \
    _Pragma("unroll")                                                            \
    for (int ca_=0; ca_<4; ++ca_) {                                              \
        const int row_ = ca_*32 + wv*8 + (lane>>3);                              \
        const int px_  = p0 + row_;                                              \
        const int pad_ = GP + px_ + (px_>>5);                                    \
        const int g_   = (lane&7) ^ (lane>>3);                                   \
        gld16(ebB + (size_t)(pad_ + off_)*128 + c0_ + g_*8,                      \
              (char*)As[buf] + (ca_*32 + wv*8)*128 + lane*16);                   \
    }                                                                            \
    _Pragma("unroll")                                                            \
    for (int cb_=0; cb_<4; ++cb_) {                                              \
        const int row_ = cb_*32 + wv*8 + (lane>>3);                              \
        gld16(wbB + (size_t)row_*512 + (ks)*64 + (lane&7)*8,                     \
              (char*)Bs[buf] + (cb_*32 + wv*8)*128 + lane*16);                   \
    }                                                                            \
} while(0)

#define W2COMP(buf) do {                                                         \
    _Pragma("unroll")                                                            \
    for (int k2_=0; k2_<2; ++k2_) {                                              \
        short8v wf_[4], pf_[4];                                                  \
        const int sl_ = ((k2_*4 + lg) ^ (lr & 7)) * 8;                           \
        _Pragma("unroll")                                                        \
        for (int f_=0; f_<4; ++f_)                                               \
            wf_[f_] = *(const short8v*)&Bs[buf][(chh*64 + f_*16 + lr)*64 + sl_]; \
        _Pragma("unroll")                                                        \
        for (int m_=0; m_<4; ++m_)                                               \
            pf_[m_] = *(const short8v*)&As[buf][(pxh*64 + m_*16 + lr)*64 + sl_]; \
        __builtin_amdgcn_s_setprio(1);                                           \
        _Pragma("unroll")                                                        \
        for (int f_=0; f_<4; ++f_)                                               \
            _Pragma("unroll")                                                    \
            for (int m_=0; m_<4; ++m_)                                           \
                acc[f_][m_] = __builtin_amdgcn_mfma_f32_16x16x32_bf16(wf_[f_], pf_[m_], acc[f_][m_],0,0,0); \
        __builtin_amdgcn_s_setprio(0);                                           \
    }                                                                            \
} while(0)

__global__ __launch_bounds__(256)
void convw(const u16* __restrict__ Wb, const float* __restrict__ bias,
           const u16* __restrict__ Ein, u16* __restrict__ out0,
           u16* __restrict__ Sio)
{
    constexpr int NS = 8;              // K=512, BK=64, BM=128, NB=128
    __shared__ u16 As[2][128*64];      // 32 KB
    __shared__ u16 Bs[2][128*64];      // 32 KB
    const int tid = threadIdx.x;
    // grid (8,2,32) = 512; XCD-bijective swizzle
    int w = blockIdx.x + (blockIdx.y << 3) + (blockIdx.z << 4);
    w = (w & 7)*64 + (w >> 3);
    const int p0  = (w & 7)*128;
    const int byy = (w >> 3) & 1;
    const int b   = w >> 4;
    const int cb0 = byy*64;
    const int wv = tid>>6, lane = tid&63, lr = lane&15, lg = lane>>4;
    const int pxh = wv&1, chh = wv>>1;
    const u16* ebB = Ein + (size_t)b*PB*128;
    const u16* wbB = Wb + (size_t)byy*128*512;
    f32x4 acc[4][4] = {};

    W2STAGE(0, 0);
    asm volatile("s_waitcnt vmcnt(0)" ::: "memory");
    __builtin_amdgcn_s_barrier();
    __builtin_amdgcn_sched_barrier(0);
    #pragma unroll
    for (int ks = 0; ks < NS; ++ks) {
        if (ks + 1 < NS) W2STAGE(ks+1, (ks+1)&1);
        W2COMP(ks&1);
        asm volatile("s_waitcnt vmcnt(0)" ::: "memory");
        __builtin_amdgcn_s_barrier();
        __builtin_amdgcn_sched_barrier(0);
    }

    // gate epilogue: acc[f][m] (f=0,1 t1; f=2,3 t2)
    #pragma unroll
    for (int f=0; f<2; ++f) {
        const int c = cb0 + chh*32 + f*16 + lg*4;
        const float4 b1 = *(const float4*)(bias + c);
        const float4 b2 = *(const float4*)(bias + 128 + c);
        #pragma unroll
        for (int m=0; m<4; ++m) {
            const int px = p0 + pxh*64 + m*16 + lr;
            const int pad = GP + px + (px>>5);
            u16* sp = Sio + ((size_t)b*PB + pad)*128 + c;
            const ushort4 sv = *(const ushort4*)sp;
            const float o0 = bf2f(sv.x) + (acc[f][m][0]+b1.x)*sig_f(acc[f+2][m][0]+b2.x);
            const float o1 = bf2f(sv.y) + (acc[f][m][1]+b1.y)*sig_f(acc[f+2][m][1]+b2.y);
            const float o2 = bf2f(sv.z) + (acc[f][m][2]+b1.z)*sig_f(acc[f+2][m][2]+b2.z);
            const float o3 = bf2f(sv.w) + (acc[f][m][3]+b1.w)*sig_f(acc[f+2][m][3]+b2.w);
            ushort4 so;
            so.x=f2bf(o0); so.y=f2bf(o1); so.z=f2bf(o2); so.w=f2bf(o3);
            *(ushort4*)sp = so;
            ushort4 e;
            e.x=f2bf(elu_f(o0)); e.y=f2bf(elu_f(o1)); e.z=f2bf(elu_f(o2)); e.w=f2bf(elu_f(o3));
            *(ushort4*)(out0 + ((size_t)b*PB + pad)*128 + c) = e;
        }
    }
}

// ---------------------------------------------------------------------------
// Head 1x1 GEMM (r12-proven)
// ---------------------------------------------------------------------------
template<int EPI, int DUAL>
__global__ __launch_bounds__(256)
void headg(const u16* __restrict__ Wh,
           const float* __restrict__ bias0, const float* __restrict__ bias1,
           const u16* __restrict__ in0, const u16* __restrict__ in1,
           u16* __restrict__ dst0, u16* __restrict__ dst1,
           const u16* __restrict__ aux, const float* __restrict__ xres,
           float* __restrict__ fout)
{
    constexpr int NY = DUAL ? 2 : 1;
    constexpr int NWG = 16*NY*32;
    __shared__ u16 As[2][64*64];
    __shared__ u16 Bs[2][128*64];
    const int tid = threadIdx.x;
    int w = blockIdx.x + (blockIdx.y << 4) + blockIdx.z * (16*NY);
    w = (w & 7)*(NWG >> 3) + (w >> 3);
    const int p0 = (w & 15)*64;
    const int by = DUAL ? ((w >> 4) & 1) : 0;
    const int b  = DUAL ? (w >> 5) : (w >> 4);
    const int wv = tid>>6, lane = tid&63, lr = lane&15, lg = lane>>4;
    const int pxh = wv&1, chh = wv>>1;
    const u16* wsrcB = Wh + (size_t)by*16384;
    const float* bias = (DUAL && by) ? bias1 : bias0;
    const u16* inB = (DUAL && by) ? in1 : in0;
    f32x4 acc[4][2] = {};

    auto HSTAGE = [&](int ks, int buf) {
        #pragma unroll
        for (int ca=0; ca<2; ++ca) {
            const int row = ca*32 + wv*8 + (lane>>3);
            const int px = p0 + row;
            size_t aoff;
            if (DUAL && by) aoff = (size_t)b*PB + (GP + px + (px>>5));
            else            aoff = (size_t)b*HW + px;
            const int g = (lane&7) ^ (lane>>3);
            gld16(inB + aoff*128 + ks*64 + g*8,
                  (char*)As[buf] + (ca*32 + wv*8)*128 + lane*16);
        }
        #pragma unroll
        for (int cb=0; cb<4; ++cb) {
            const int row = cb*32 + wv*8 + (lane>>3);
            gld16(wsrcB + (size_t)row*128 + ks*64 + (lane&7)*8,
                  (char*)Bs[buf] + (cb*32 + wv*8)*128 + lane*16);
        }
    };
    auto HCOMP = [&](int buf) {
        #pragma unroll
        for (int k2=0; k2<2; ++k2) {
            short8v wf[4], pf[2];
            const int sl = ((k2*4 + lg) ^ (lr & 7)) * 8;
            #pragma unroll
            for (int f=0; f<4; ++f)
                wf[f] = *(const short8v*)&Bs[buf][(chh*64 + f*16 + lr)*64 + sl];
            #pragma unroll
            for (int m=0; m<2; ++m)
                pf[m] = *(const short8v*)&As[buf][(pxh*32 + m*16 + lr)*64 + sl];
            __builtin_amdgcn_s_setprio(1);
            #pragma unroll
            for (int f=0; f<4; ++f)
                #pragma unroll
                for (int m=0; m<2; ++m)
                    acc[f][m] = __builtin_amdgcn_mfma_f32_16x16x32_bf16(wf[f], pf[m], acc[f][m],0,0,0);
            __builtin_amdgcn_s_setprio(0);
        }
    };

    HSTAGE(0, 0);
    HSTAGE(1, 1);
    asm volatile("s_waitcnt vmcnt(6)" ::: "memory");
    __builtin_amdgcn_s_barrier();
    __builtin_amdgcn_sched_barrier(0);
    HCOMP(0);
    asm volatile("s_waitcnt vmcnt(0)" ::: "memory");
    __builtin_amdgcn_s_barrier();
    __builtin_amdgcn_sched_barrier(0);
    HCOMP(1);

    #pragma unroll
    for (int f=0; f<4; ++f) {
        const int c = chh*64 + f*16 + lg*4;
        #pragma unroll
        for (int m=0; m<2; ++m) {
            const int px = p0 + pxh*32 + m*16 + lr;
            if constexpr (EPI == 3) {
                const float* bp = bias + c;
                #pragma unroll
                for (int r=0; r<4; ++r) {
                    const size_t o = ((size_t)b*128 + c + r)*HW + px;
                    fout[o] = elu_f(acc[f][m][r] + bp[r]) + xres[o];
                }
            } else {
                const float4 bb = *(const float4*)(bias + c);
                const float v0=acc[f][m][0]+bb.x, v1=acc[f][m][1]+bb.y;
                const float v2=acc[f][m][2]+bb.z, v3=acc[f][m][3]+bb.w;
                ushort4 e;
                if constexpr (EPI == 2) {
                    const ushort4 c4 = *(const ushort4*)(aux + ((size_t)b*HW+px)*128 + c);
                    e.x = f2bf(elu_f(bf2f(c4.x) + elu_f(v0)));
                    e.y = f2bf(elu_f(bf2f(c4.y) + elu_f(v1)));
                    e.z = f2bf(elu_f(bf2f(c4.z) + elu_f(v2)));
                    e.w = f2bf(elu_f(bf2f(c4.w) + elu_f(v3)));
                } else {
                    e.x=f2bf(elu_f(v0)); e.y=f2bf(elu_f(v1));
                    e.z=f2bf(elu_f(v2)); e.w=f2bf(elu_f(v3));
                }
                u16* dst = (DUAL && by) ? dst1 : dst0;
                *(ushort4*)(dst + ((size_t)b*HW+px)*128 + c) = e;
            }
        }
    }
}

// ---------------------------------------------------------------------------
// qkv GEMM (r12-proven)
// ---------------------------------------------------------------------------
__global__ __launch_bounds__(256)
void qkvg(const u16* __restrict__ Wq, const float* __restrict__ qkvw,
          const float* __restrict__ bias, const u16* __restrict__ Sb,
          u16* __restrict__ qo, u16* __restrict__ ko, u16* __restrict__ vo)
{
    __shared__ u16 As[2][64*64];
    __shared__ u16 Bs[2][192*64];
    const int tid = threadIdx.x;
    int w = blockIdx.x + (blockIdx.z << 4);
    w = (w & 7)*64 + (w >> 3);
    const int p0 = (w & 15)*64;
    const int b  = w >> 4;
    const int wv = tid>>6, lane = tid&63, lr = lane&15, lg = lane>>4;
    const int pxh = wv&1, chh = wv>>1;
    const u16* ebB = Sb + (size_t)b*PB*128;
    f32x4 acc[6][2] = {};

    auto QSTAGE = [&](int ks, int buf) {
        #pragma unroll
        for (int ca=0; ca<2; ++ca) {
            const int row = ca*32 + wv*8 + (lane>>3);
            const int px = p0 + row;
            const int pad = GP + px + (px>>5);
            const int g = (lane&7) ^ (lane>>3);
            gld16(ebB + (size_t)pad*128 + ks*64 + g*8,
                  (char*)As[buf] + (ca*32 + wv*8)*128 + lane*16);
        }
        #pragma unroll
        for (int cb=0; cb<6; ++cb) {
            const int row = cb*32 + wv*8 + (lane>>3);
            gld16(Wq + (size_t)row*128 + ks*64 + (lane&7)*8,
                  (char*)Bs[buf] + (cb*32 + wv*8)*128 + lane*16);
        }
    };
    auto QCOMP = [&](int buf) {
        #pragma unroll
        for (int k2=0; k2<2; ++k2) {
            short8v wf[6], pf[2];
            const int sl = ((k2*4 + lg) ^ (lr & 7)) * 8;
            #pragma unroll
            for (int f=0; f<6; ++f)
                wf[f] = *(const short8v*)&Bs[buf][(chh*96 + f*16 + lr)*64 + sl];
            #pragma unroll
            for (int m=0; m<2; ++m)
                pf[m] = *(const short8v*)&As[buf][(pxh*32 + m*16 + lr)*64 + sl];
            __builtin_amdgcn_s_setprio(1);
            #pragma unroll
            for (int f=0; f<6; ++f)
                #pragma unroll
                for (int m=0; m<2; ++m)
                    acc[f][m] = __builtin_amdgcn_mfma_f32_16x16x32_bf16(wf[f], pf[m], acc[f][m],0,0,0);
            __builtin_amdgcn_s_setprio(0);
        }
    };

    QSTAGE(0, 0);
    QSTAGE(1, 1);
    asm volatile("s_waitcnt vmcnt(8)" ::: "memory");
    __builtin_amdgcn_s_barrier();
    __builtin_amdgcn_sched_barrier(0);
    QCOMP(0);
    asm volatile("s_waitcnt vmcnt(0)" ::: "memory");
    __builtin_amdgcn_s_barrier();
    __builtin_amdgcn_sched_barrier(0);
    QCOMP(1);

    #pragma unroll
    for (int f=0; f<6; ++f) {
        const int row0 = chh*96 + f*16;
        if (row0 >= 160) continue;
        #pragma unroll
        for (int m=0; m<2; ++m) {
            const int px = p0 + pxh*32 + m*16 + lr;
            const float pyv = (float)(px>>5)*0.03125f - 0.5f;
            const float pxv = (float)(px&31)*0.03125f - 0.5f;
            #pragma unroll
            for (int r=0; r<4; ++r) {
                const int mm = row0 + lg*4 + r;
                const float val = acc[f][m][r] + bias[mm]
                                + qkvw[(size_t)mm*130 + 128]*pyv
                                + qkvw[(size_t)mm*130 + 129]*pxv;
                if (mm < 16)      qo[((size_t)b*HW+px)*16 + mm]        = f2bf(0.25f*val);
                else if (mm < 32) ko[((size_t)b*HW+px)*16 + (mm-16)]   = f2bf(val);
                else              vo[((size_t)b*128 + (mm-32))*HW + px] = f2bf(val);
            }
        }
    }
}

// ---------------------------------------------------------------------------
// MFMA causal attention (r12-proven: hi/lo pairing, 36/20 strides)
// ---------------------------------------------------------------------------
__global__ __launch_bounds__(256)
void attn_mfma(const u16* __restrict__ qb, const u16* __restrict__ kb,
               const u16* __restrict__ vb, u16* __restrict__ ob)
{
    __shared__ u16 ks_[2][32*20];
    __shared__ u16 vs_[2][128*36];
    const int tid = threadIdx.x;
    const int bid = blockIdx.x;              // 0..511
    const int s  = bid >> 5;
    const int b  = bid & 31;
    const int tp = (s < 8) ? (15 - s) : (s - 8);
    const int wv = tid>>6, lane = tid&63;
    const int lq = lane&31, hf = lane>>5;
    const int qt = tp*2 + (wv&1);
    const int dh = wv>>1;
    const int q0 = qt*32;
    const int NC = tp*2 + 2;

    const short8v Qf = *(const short8v*)(qb + ((size_t)b*HW + q0 + lq)*16 + hf*8);
    f32x16 acc[2] = {{},{}};
    float mrun = -1e30f, lrun = 0.f;
    unsigned diagm = 0;
    #pragma unroll
    for (int r=0; r<16; ++r) {
        const int row = (r&3) + 8*(r>>2) + 4*hf;
        diagm |= (row <= lq) ? (1u<<r) : 0u;
    }
    const f32x16 zc = {};

    const int vrow = tid>>2, vg = tid&3;
    const int krow = tid>>1, kg = tid&1;
    const u16* vbb = vb + (size_t)b*128*HW;
    const u16* kbb = kb + (size_t)b*HW*16;
    uint4 rv0A, rv1A, rkA, rv0B, rv1B, rkB;

#define AGLD(c, RV0, RV1, RK) do {                                             \
    const int kv0_ = (c)*32;                                                   \
    RV0 = *(const uint4*)(vbb + (size_t)vrow*HW + kv0_ + vg*8);                \
    RV1 = *(const uint4*)(vbb + (size_t)(64+vrow)*HW + kv0_ + vg*8);           \
    if (tid < 64) RK = *(const uint4*)(kbb + (size_t)(kv0_ + krow)*16 + kg*8); \
} while(0)
#define ASST(buf, RV0, RV1, RK) do {                                           \
    *(uint4*)&vs_[buf][vrow*36 + vg*8] = RV0;                                  \
    *(uint4*)&vs_[buf][(64+vrow)*36 + vg*8] = RV1;                             \
    if (tid < 64) *(uint4*)&ks_[buf][krow*20 + kg*8] = RK;                     \
} while(0)

    auto CHUNK = [&](int buf, int cc) {
        if (cc > qt) return;
        const short8v Kf = *(const short8v*)&ks_[buf][lq*20 + hf*8];
        f32x16 st = __builtin_amdgcn_mfma_f32_32x32x16_bf16(Kf, Qf, zc, 0,0,0);
        if (cc == qt) {
            #pragma unroll
            for (int r=0;r<16;++r) st[r] = ((diagm>>r)&1) ? st[r] : -1e30f;
        }
        float mc = st[0];
        #pragma unroll
        for (int r=1;r<16;++r) mc = fmaxf(mc, st[r]);
        mc = fmaxf(mc, __shfl_xor(mc, 32));
        if (!__all(mc <= mrun)) {
            const float mnew = fmaxf(mrun, mc);
            const float corr = __expf(mrun - mnew);
            lrun *= corr;
            #pragma unroll
            for (int f=0;f<2;++f)
                #pragma unroll
                for (int r=0;r<16;++r) acc[f][r] *= corr;
            mrun = mnew;
        }
        float ps[16]; float lsum = 0.f;
        #pragma unroll
        for (int r=0;r<16;++r){ ps[r]=__expf(st[r]-mrun); lsum += ps[r]; }
        lrun += lsum + __shfl_xor(lsum, 32);
        unsigned pk[8], sw[8];
        #pragma unroll
        for (int i=0;i<8;++i)
            pk[i] = (unsigned)f2bf(ps[2*i]) | ((unsigned)f2bf(ps[2*i+1])<<16);
        #pragma unroll
        for (int i=0;i<8;++i) sw[i] = __shfl_xor(pk[i], 32);
        union { unsigned u[4]; short8v v; } B1, B2;
        B1.u[0]=hf?sw[2]:pk[0]; B1.u[1]=hf?sw[3]:pk[1];
        B1.u[2]=hf?pk[2]:sw[0]; B1.u[3]=hf?pk[3]:sw[1];
        B2.u[0]=hf?sw[6]:pk[4]; B2.u[1]=hf?sw[7]:pk[5];
        B2.u[2]=hf?pk[6]:sw[4]; B2.u[3]=hf?pk[7]:sw[5];
        #pragma unroll
        for (int f=0;f<2;++f) {
            const int fg = dh*2 + f;
            const short8v A1 = *(const short8v*)&vs_[buf][(fg*32+lq)*36 + hf*8];
            const short8v A2 = *(const short8v*)&vs_[buf][(fg*32+lq)*36 + 16 + hf*8];
            acc[f] = __builtin_amdgcn_mfma_f32_32x32x16_bf16(A1, B1.v, acc[f],0,0,0);
            acc[f] = __builtin_amdgcn_mfma_f32_32x32x16_bf16(A2, B2.v, acc[f],0,0,0);
        }
    };

    AGLD(0, rv0A, rv1A, rkA); ASST(0, rv0A, rv1A, rkA);
    AGLD(1, rv0B, rv1B, rkB);
    __syncthreads();
    for (int c = 0; c < NC; c += 2) {
        CHUNK(0, c);
        ASST(1, rv0B, rv1B, rkB);
        if (c+2 < NC) AGLD(c+2, rv0A, rv1A, rkA);
        __syncthreads();
        CHUNK(1, c+1);
        if (c+2 < NC) {
            ASST(0, rv0A, rv1A, rkA);
            if (c+3 < NC) AGLD(c+3, rv0B, rv1B, rkB);
        }
        __syncthreads();
    }
#undef AGLD
#undef ASST

    const float inv = 1.f / lrun;
    u16* orow = ob + ((size_t)b*HW + q0 + lq)*128;
    #pragma unroll
    for (int f=0; f<2; ++f) {
        #pragma unroll
        for (int g=0; g<4; ++g) {
            const int d0 = (dh*2+f)*32 + 8*g + 4*hf;
            ushort4 o4;
            o4.x = f2bf(acc[f][g*4+0]*inv);
            o4.y = f2bf(acc[f][g*4+1]*inv);
            o4.z = f2bf(acc[f][g*4+2]*inv);
            o4.w = f2bf(acc[f][g*4+3]*inv);
            *(ushort4*)(orow + d0) = o4;
        }
    }
}

extern "C" void kernel_launch(void* const* d_in, const int* in_sizes, int n_in,
                              void* d_out, int out_size, void* d_ws, size_t ws_size,
                              hipStream_t stream) {
    const float* x    = (const float*)d_in[0];
    const float* rw1  = (const float*)d_in[1];
    const float* rb1  = (const float*)d_in[2];
    const float* rw2  = (const float*)d_in[3];
    const float* rb2  = (const float*)d_in[4];
    const float* qkvw = (const float*)d_in[5];
    const float* qkvb = (const float*)d_in[6];
    const float* apw  = (const float*)d_in[7];
    const float* apb  = (const float*)d_in[8];
    const float* ocw  = (const float*)d_in[9];
    const float* ocb  = (const float*)d_in[10];
    const float* oaw  = (const float*)d_in[11];
    const float* oab  = (const float*)d_in[12];
    const float* opw  = (const float*)d_in[13];
    const float* opb  = (const float*)d_in[14];
    float* out = (float*)d_out;
    float* ws = (float*)d_ws;

    u16* Sb  = (u16*)ws;
    u16* Eb  = (u16*)(ws + 2293760);
    u16* E2  = (u16*)(ws + 4587520);
    u16* ob  = (u16*)(ws + 6881280);
    u16* qb  = (u16*)(ws + 8978432);
    u16* kb  = (u16*)(ws + 9240576);
    u16* vb  = (u16*)(ws + 9502720);
    u16* w1b = (u16*)(ws + 11599872);
    u16* w2b = (u16*)(ws + 11796480);
    u16* whs = (u16*)(ws + 12189696);
    u16* qws = (u16*)(ws + 12222464);
    u16* Ea  = (u16*)(ws + 12234752);
    u16* c1p = (u16*)(ws + 14331904);
    u16* Es  = ob;

    dim3 blk(256);
    wconv<<<1888, blk, 0, stream>>>(rw1, rw2, apw, ocw, oaw, opw, qkvw,
                                    w1b, w2b, whs, qws, Eb, E2);
    init_k<<<dim3(32, 32), blk, 0, stream>>>(x, Sb, Eb);
    for (int i = 0; i < 6; ++i) {
        convg<<<dim3(16,1,32), blk, 0, stream>>>(
            w1b + (size_t)i*65536, rb1 + i*128, Eb, E2);
        convw<<<dim3(8,2,32), blk, 0, stream>>>(
            w2b + (size_t)i*131072, rb2 + i*256, E2, Eb, Sb);
    }
    qkvg<<<dim3(16,1,32), blk, 0, stream>>>(qws, qkvw, qkvb, Sb, qb, kb, vb);
    attn_mfma<<<512, blk, 0, stream>>>(qb, kb, vb, ob);
    headg<0,1><<<dim3(16,2,32), blk, 0, stream>>>(
        whs, apb, ocb, ob, Eb, Ea, c1p, nullptr, nullptr, nullptr);
    headg<2,0><<<dim3(16,1,32), blk, 0, stream>>>(
        whs + 32768, oab, nullptr, Ea, nullptr, Es, nullptr, c1p, nullptr, nullptr);
    headg<3,0><<<dim3(16,1,32), blk, 0, stream>>>(
        whs + 49152, opb, nullptr, Es, nullptr, nullptr, nullptr, nullptr, x, out);
}